// Round 5
// baseline (263.099 us; speedup 1.0000x reference)
//
#include <hip/hip_runtime.h>
#include <hip/hip_bf16.h>
#include <hip/hip_cooperative_groups.h>
#include <math.h>

namespace cg = cooperative_groups;

#define B 8
#define S 2048
#define IN_DIM 8
#define EMB 512
#define HEADS 8
#define HDIM 64
#define HALF 256
#define NCLS 3
#define NCHUNK 32   // t-chunks of 64

// workspace layout (float offsets)
#define WS_KQ    0            // [B][HEADS][EMB]   (hi half used)      = 32768
#define WS_COEF1 32768        // [B][HEADS][12]  (a[0..7], c0, c1)     = 768
#define WS_PM    33536        // [B][32][HEADS][16] (m,Z,ta,fa[8])     = 32768
#define WS_PS    66304        // [B][32][HEADS][256] S-partials        = 524288
#define WS_OH    590592       // [B][EMB]                              = 4096
#define WS_OP    594688       // [B][EMB]                              = 4096

struct KP {
    const float *feat, *ts, *Wf, *bf, *Wl, *bl, *Wp, *bp, *Wq, *bq,
                *Wk, *bk, *Wv, *bv, *Wo, *bo, *td, *W1, *b1, *W2, *b2;
    float *ws, *out;
};

// Single cooperative kernel: 256 blocks x 256 threads (1 block/CU).
// Phases: A=head prep (64 blk) | B=chunk scores+softmax partials (256 blk)
//       | C=flash merge + wx + Wv gemv (64 blk) | D=Wo gemv (64 blk) | E=tail (8 blk)
__global__ __launch_bounds__(256, 1) void k_fused(KP p)
{
    cg::grid_group grid = cg::this_grid();
    const int blk = blockIdx.x;
    const int tid = threadIdx.x;
    float* ws = p.ws;

    // ---------------- phase A: per (b,h) head prep ----------------
    __shared__ float xl[EMB];
    __shared__ __align__(16) float qc[HDIM];
    __shared__ float kqA[EMB];
    __shared__ float redA[4][64];
    __shared__ float red10[4][12];

    if (blk < B*HEADS) {
        const int b = blk >> 3, h = blk & 7;
        const int bh = b*HEADS + h;
        // x at last position
        {
            const float tl = p.ts[b*S + (S-1)];
            float fv[IN_DIM];
            #pragma unroll
            for (int i = 0; i < IN_DIM; ++i) fv[i] = p.feat[(b*S + (S-1))*IN_DIM + i];
            #pragma unroll
            for (int r = 0; r < 2; ++r) {
                const int e = tid + r*256;
                float acc = p.bf[e];
                #pragma unroll
                for (int i = 0; i < IN_DIM; ++i) acc += fv[i]*p.Wf[i*EMB + e];
                if (r == 0) acc += tl*p.Wl[e] + p.bl[e];
                else        acc += __sinf(tl*p.Wp[e-HALF] + p.bp[e-HALF]);
                xl[e] = acc;
            }
        }
        __syncthreads();
        // q-chunk (4-way split-K)
        {
            const int eo = tid & 63, jq = tid >> 6;
            float acc = (jq == 0) ? p.bq[h*HDIM + eo] : 0.f;
            #pragma unroll 8
            for (int j = jq*128; j < jq*128 + 128; ++j)
                acc += xl[j]*p.Wq[j*EMB + h*HDIM + eo];
            redA[jq][eo] = acc;
        }
        __syncthreads();
        if (tid < HDIM) qc[tid] = redA[0][tid]+redA[1][tid]+redA[2][tid]+redA[3][tid];
        __syncthreads();
        // kq[j] = Wk[j, h*64:+64] . qc
        {
            #pragma unroll
            for (int r = 0; r < 2; ++r) {
                const int j = tid + r*256;
                const float4* wr = (const float4*)(p.Wk + j*EMB + h*HDIM);
                const float4* qv = (const float4*)qc;
                float acc = 0.f;
                #pragma unroll
                for (int k = 0; k < 16; ++k) {
                    const float4 w = wr[k], q4 = qv[k];
                    acc += w.x*q4.x + w.y*q4.y + w.z*q4.z + w.w*q4.w;
                }
                kqA[j] = acc;
                if (j >= HALF) ws[WS_KQ + bh*EMB + j] = acc;
            }
        }
        __syncthreads();
        // coef
        {
            float a[IN_DIM] = {0.f,0.f,0.f,0.f,0.f,0.f,0.f,0.f};
            float c0 = 0.f, c1 = 0.f;
            #pragma unroll
            for (int r = 0; r < 2; ++r) {
                const int e = tid + r*256;
                const float kv = kqA[e];
                #pragma unroll
                for (int i = 0; i < IN_DIM; ++i) a[i] += p.Wf[i*EMB + e]*kv;
                c0 += p.bf[e]*kv;
                if (r == 0) { c0 += p.bl[e]*kv; c1 += p.Wl[e]*kv; }
            }
            if (tid < HDIM) c0 += qc[tid]*p.bk[h*HDIM + tid];
            #pragma unroll
            for (int off = 32; off >= 1; off >>= 1) {
                #pragma unroll
                for (int i = 0; i < IN_DIM; ++i) a[i] += __shfl_xor(a[i], off, 64);
                c0 += __shfl_xor(c0, off, 64);
                c1 += __shfl_xor(c1, off, 64);
            }
            const int wid = tid >> 6, lane = tid & 63;
            if (lane == 0) {
                #pragma unroll
                for (int i = 0; i < IN_DIM; ++i) red10[wid][i] = a[i];
                red10[wid][8] = c0; red10[wid][9] = c1;
            }
            __syncthreads();
            if (tid < 10)
                ws[WS_COEF1 + bh*12 + tid] =
                    red10[0][tid]+red10[1][tid]+red10[2][tid]+red10[3][tid];
        }
    }
    __threadfence();
    grid.sync();

    // ---------------- phase B: per (b, chunk) scores + partials ----------------
    __shared__ float sin_l[256*65];            // [j][t] stride 65
    __shared__ __align__(16) float kqh[HEADS][256];
    __shared__ __align__(16) float w_l[64*8];  // [t][h]
    __shared__ float tv_l[64];
    __shared__ float f_l[64*9];                // [t][i] stride 9
    __shared__ float cfB[96];                  // [h][12]
    {
        const int c = blk & 31;
        const int b = blk >> 5;
        const int t0 = c*64;

        if (tid < 64) tv_l[tid] = p.ts[b*S + t0 + tid];
        for (int idx = tid; idx < 64*IN_DIM; idx += 256) {
            const int tt = idx >> 3, i = idx & 7;
            f_l[tt*9 + i] = p.feat[(b*S + t0 + tt)*IN_DIM + i];
        }
        for (int idx = tid; idx < HEADS*256; idx += 256)
            ((float*)kqh)[idx] = ws[WS_KQ + (b*HEADS + (idx >> 8))*EMB + HALF + (idx & 255)];
        if (tid < 96) cfB[tid] = ws[WS_COEF1 + b*96 + tid];
        const float tl = p.ts[b*S + (S-1)];
        const float tdc = p.td[0];
        __syncthreads();

        // sin table (computed once, used for scores AND S-partials)
        {
            const float wj = p.Wp[tid], bj = p.bp[tid];
            float* srow = sin_l + tid*65;
            #pragma unroll 4
            for (int tt = 0; tt < 64; ++tt)
                srow[tt] = __sinf(tv_l[tt]*wj + bj);
        }
        __syncthreads();

        // scores for (t, h0) and (t, h0+4)
        const int t = tid & 63, h0 = tid >> 6;
        const float tv = tv_l[t];
        float fv[IN_DIM];
        #pragma unroll
        for (int i = 0; i < IN_DIM; ++i) fv[i] = f_l[t*9 + i];
        const float dec = __expf(-tdc*fabsf(tl - tv));
        float sc[2];
        {
            float acc0 = 0.f, acc1 = 0.f;
            const float4* kq0 = (const float4*)&kqh[h0][0];
            const float4* kq1 = (const float4*)&kqh[h0+4][0];
            #pragma unroll 4
            for (int j4 = 0; j4 < 64; ++j4) {
                const float s0 = sin_l[(j4*4+0)*65 + t];
                const float s1 = sin_l[(j4*4+1)*65 + t];
                const float s2 = sin_l[(j4*4+2)*65 + t];
                const float s3 = sin_l[(j4*4+3)*65 + t];
                const float4 ka = kq0[j4], kb = kq1[j4];
                acc0 += s0*ka.x + s1*ka.y + s2*ka.z + s3*ka.w;
                acc1 += s0*kb.x + s1*kb.y + s2*kb.z + s3*kb.w;
            }
            #pragma unroll
            for (int pp = 0; pp < 2; ++pp) {
                const int h = h0 + pp*4;
                float base = cfB[h*12+8] + tv*cfB[h*12+9];
                #pragma unroll
                for (int i = 0; i < IN_DIM; ++i) base += fv[i]*cfB[h*12+i];
                sc[pp] = (base + ((pp == 0) ? acc0 : acc1))*0.125f*dec;
            }
        }
        // per-wave local softmax stats
        #pragma unroll
        for (int pp = 0; pp < 2; ++pp) {
            const int h = h0 + pp*4;
            float m = sc[pp];
            #pragma unroll
            for (int off = 32; off >= 1; off >>= 1) m = fmaxf(m, __shfl_xor(m, off, 64));
            const float w = __expf(sc[pp] - m);
            float Z = w, ta = w*tv;
            float fa[IN_DIM];
            #pragma unroll
            for (int i = 0; i < IN_DIM; ++i) fa[i] = w*fv[i];
            #pragma unroll
            for (int off = 32; off >= 1; off >>= 1) {
                Z  += __shfl_xor(Z,  off, 64);
                ta += __shfl_xor(ta, off, 64);
                #pragma unroll
                for (int i = 0; i < IN_DIM; ++i) fa[i] += __shfl_xor(fa[i], off, 64);
            }
            w_l[t*8 + h] = w;
            if (t == 0) {
                float* pm = ws + WS_PM + ((b*NCHUNK + c)*HEADS + h)*16;
                pm[0] = m; pm[1] = Z; pm[2] = ta;
                #pragma unroll
                for (int i = 0; i < IN_DIM; ++i) pm[3+i] = fa[i];
            }
        }
        __syncthreads();
        // S_c[h][j] = sum_t w[t][h] * sin[j][t]
        {
            const int j = tid;
            float accS[HEADS] = {0.f,0.f,0.f,0.f,0.f,0.f,0.f,0.f};
            const float4* wv4 = (const float4*)w_l;
            const float* scol = sin_l + j*65;
            #pragma unroll 4
            for (int tt = 0; tt < 64; ++tt) {
                const float sv = scol[tt];
                const float4 wa = wv4[tt*2], wb = wv4[tt*2+1];
                accS[0] += wa.x*sv; accS[1] += wa.y*sv; accS[2] += wa.z*sv; accS[3] += wa.w*sv;
                accS[4] += wb.x*sv; accS[5] += wb.y*sv; accS[6] += wb.z*sv; accS[7] += wb.w*sv;
            }
            const int base = WS_PS + ((b*NCHUNK + c)*HEADS)*256 + j;
            #pragma unroll
            for (int h = 0; h < HEADS; ++h) ws[base + h*256] = accS[h];
        }
    }
    __threadfence();
    grid.sync();

    // ---------------- phase C: per (b,h) flash merge + wx + Wv gemv ----------------
    __shared__ float pmC[NCHUNK][12];
    __shared__ float alC[NCHUNK];
    __shared__ float cfC[10];
    __shared__ float wxC[EMB];
    if (blk < B*HEADS) {
        const int b = blk >> 3, h = blk & 7;
        for (int idx = tid; idx < NCHUNK*12; idx += 256) {
            const int c = idx / 12, k = idx % 12;
            pmC[c][k] = (k < 11) ? ws[WS_PM + ((b*NCHUNK + c)*HEADS + h)*16 + k] : 0.f;
        }
        __syncthreads();
        float m = pmC[0][0];
        #pragma unroll 8
        for (int c = 1; c < NCHUNK; ++c) m = fmaxf(m, pmC[c][0]);
        if (tid < NCHUNK) alC[tid] = __expf(pmC[tid][0] - m);
        __syncthreads();
        float Z = 0.f;
        #pragma unroll 8
        for (int c = 0; c < NCHUNK; ++c) Z += alC[c]*pmC[c][1];
        const float inv = 1.f/Z;
        if (tid < 9) {
            const int k = (tid == 8) ? 2 : 3 + tid;
            float acc = 0.f;
            #pragma unroll 8
            for (int c = 0; c < NCHUNK; ++c) acc += alC[c]*pmC[c][k];
            cfC[(tid == 8) ? 8 : tid] = acc*inv;
        }
        __syncthreads();
        {
            const int j = tid;
            float acc = 0.f;
            #pragma unroll 8
            for (int c = 0; c < NCHUNK; ++c)
                acc += alC[c]*ws[WS_PS + ((b*NCHUNK + c)*HEADS + h)*256 + j];
            float vh = p.bf[HALF + j] + acc*inv;
            float vl = p.bf[j] + cfC[8]*p.Wl[j] + p.bl[j];
            #pragma unroll
            for (int i = 0; i < IN_DIM; ++i) {
                vh += cfC[i]*p.Wf[i*EMB + HALF + j];
                vl += cfC[i]*p.Wf[i*EMB + j];
            }
            wxC[j] = vl;
            wxC[HALF + j] = vh;
        }
        __syncthreads();
        {
            const int eo = tid & 63, jq = tid >> 6;
            const int e = h*HDIM + eo;
            float acc = 0.f;
            #pragma unroll 8
            for (int j = jq*128; j < jq*128 + 128; ++j)
                acc += wxC[j]*p.Wv[j*EMB + e];
            redA[jq][eo] = acc;
        }
        __syncthreads();
        if (tid < 64)
            ws[WS_OH + b*EMB + h*HDIM + tid] =
                redA[0][tid]+redA[1][tid]+redA[2][tid]+redA[3][tid] + p.bv[h*HDIM + tid];
    }
    __threadfence();
    grid.sync();

    // ---------------- phase D: per (b,ec) Wo gemv ----------------
    __shared__ float xvD[EMB];
    if (blk < B*8) {
        const int b = blk >> 3, ec = blk & 7;
        xvD[tid]       = ws[WS_OH + b*EMB + tid];
        xvD[tid + 256] = ws[WS_OH + b*EMB + tid + 256];
        __syncthreads();
        {
            const int eo = tid & 63, jq = tid >> 6;
            const int e = ec*64 + eo;
            float acc = 0.f;
            #pragma unroll 8
            for (int j = jq*128; j < jq*128 + 128; ++j)
                acc += xvD[j]*p.Wo[j*EMB + e];
            redA[jq][eo] = acc;
        }
        __syncthreads();
        if (tid < 64)
            ws[WS_OP + b*EMB + ec*64 + tid] =
                redA[0][tid]+redA[1][tid]+redA[2][tid]+redA[3][tid] + p.bo[ec*64 + tid];
    }
    __threadfence();
    grid.sync();

    // ---------------- phase E: per b tail (W1+relu, W2) ----------------
    __shared__ float xvE[EMB];
    __shared__ float red3E[4][3];
    if (blk < B) {
        const int b = blk;
        xvE[tid]       = ws[WS_OP + b*EMB + tid];
        xvE[tid + 256] = ws[WS_OP + b*EMB + tid + 256];
        __syncthreads();
        float acc = p.b1[tid];
        #pragma unroll 8
        for (int j = 0; j < EMB; ++j) acc += xvE[j]*p.W1[j*HALF + tid];
        const float hv = fmaxf(acc, 0.f);
        float p0 = hv*p.W2[tid*NCLS + 0];
        float p1 = hv*p.W2[tid*NCLS + 1];
        float p2 = hv*p.W2[tid*NCLS + 2];
        #pragma unroll
        for (int off = 32; off >= 1; off >>= 1) {
            p0 += __shfl_xor(p0, off, 64);
            p1 += __shfl_xor(p1, off, 64);
            p2 += __shfl_xor(p2, off, 64);
        }
        const int wid = tid >> 6;
        if ((tid & 63) == 0) { red3E[wid][0] = p0; red3E[wid][1] = p1; red3E[wid][2] = p2; }
        __syncthreads();
        if (tid < NCLS)
            p.out[b*NCLS + tid] = red3E[0][tid]+red3E[1][tid]+red3E[2][tid]+red3E[3][tid] + p.b2[tid];
    }
}

extern "C" void kernel_launch(void* const* d_in, const int* in_sizes, int n_in,
                              void* d_out, int out_size, void* d_ws, size_t ws_size,
                              hipStream_t stream)
{
    KP p;
    p.feat = (const float*)d_in[0];
    p.ts   = (const float*)d_in[1];
    p.Wf = (const float*)d_in[2];
    p.bf = (const float*)d_in[3];
    p.Wl = (const float*)d_in[4];
    p.bl = (const float*)d_in[5];
    p.Wp = (const float*)d_in[6];
    p.bp = (const float*)d_in[7];
    p.Wq = (const float*)d_in[8];
    p.bq = (const float*)d_in[9];
    p.Wk = (const float*)d_in[10];
    p.bk = (const float*)d_in[11];
    p.Wv = (const float*)d_in[12];
    p.bv = (const float*)d_in[13];
    p.Wo = (const float*)d_in[14];
    p.bo = (const float*)d_in[15];
    p.td = (const float*)d_in[16];
    p.W1 = (const float*)d_in[17];
    p.b1 = (const float*)d_in[18];
    p.W2 = (const float*)d_in[19];
    p.b2 = (const float*)d_in[20];
    p.ws  = (float*)d_ws;
    p.out = (float*)d_out;

    void* args[] = { &p };
    hipLaunchCooperativeKernel((const void*)k_fused, dim3(256), dim3(256),
                               args, 0, stream);
}

// Round 6
// 61.466 us; speedup vs baseline: 4.2804x; 4.2804x over previous
//
#include <hip/hip_runtime.h>
#include <hip/hip_bf16.h>
#include <math.h>

#define B 8
#define S 2048
#define IN_DIM 8
#define EMB 512
#define HEADS 8
#define HDIM 64
#define HALF 256
#define NCLS 3
#define NCHUNK 32   // t-chunks of 64

// workspace layout (float offsets)
#define WS_KQ    0            // [B][HEADS][EMB]   (hi half used)      = 32768
#define WS_COEF1 32768        // [B][HEADS][12]  (a[0..7], c0, c1)     = 768
#define WS_PM    33536        // [B][32][HEADS][16] (m,Z,ta,fa[8])     = 32768
#define WS_PS    66304        // [B][32][HEADS][256] S-partials        = 524288

// K1: per (b,h): recompute x_last -> q-chunk(h) -> kq[b][h][:] -> coef
__global__ __launch_bounds__(256) void k_head(
    const float* __restrict__ feat, const float* __restrict__ ts,
    const float* __restrict__ Wf, const float* __restrict__ bf,
    const float* __restrict__ Wl, const float* __restrict__ bl,
    const float* __restrict__ Wp, const float* __restrict__ bp,
    const float* __restrict__ Wq, const float* __restrict__ bq,
    const float* __restrict__ Wk, const float* __restrict__ bk,
    float* __restrict__ ws)
{
    const int h = blockIdx.x;
    const int b = blockIdx.y;
    const int bh = b*HEADS + h;
    const int tid = threadIdx.x;
    __shared__ float xl[EMB];
    __shared__ __align__(16) float qc[HDIM];
    __shared__ float kq[EMB];
    __shared__ float red[4][64];
    __shared__ float red10[4][12];

    // phase 0: x at last position
    {
        const float tl = ts[b*S + (S-1)];
        float fv[IN_DIM];
        #pragma unroll
        for (int i = 0; i < IN_DIM; ++i) fv[i] = feat[(b*S + (S-1))*IN_DIM + i];
        #pragma unroll
        for (int r = 0; r < 2; ++r) {
            const int e = tid + r*256;
            float acc = bf[e];
            #pragma unroll
            for (int i = 0; i < IN_DIM; ++i) acc += fv[i]*Wf[i*EMB + e];
            if (r == 0) acc += tl*Wl[e] + bl[e];
            else        acc += __sinf(tl*Wp[e-HALF] + bp[e-HALF]);
            xl[e] = acc;
        }
    }
    __syncthreads();
    // phase 1: q-chunk for this head (4-way split-K)
    {
        const int eo = tid & 63, jq = tid >> 6;
        float acc = (jq == 0) ? bq[h*HDIM + eo] : 0.f;
        #pragma unroll 8
        for (int j = jq*128; j < jq*128 + 128; ++j)
            acc += xl[j]*Wq[j*EMB + h*HDIM + eo];
        red[jq][eo] = acc;
    }
    __syncthreads();
    if (tid < HDIM) qc[tid] = red[0][tid]+red[1][tid]+red[2][tid]+red[3][tid];
    __syncthreads();
    // phase 2: kq[j] = Wk[j, h*64:+64] . qc
    {
        #pragma unroll
        for (int r = 0; r < 2; ++r) {
            const int j = tid + r*256;
            const float4* wr = (const float4*)(Wk + j*EMB + h*HDIM);
            const float4* qv = (const float4*)qc;
            float acc = 0.f;
            #pragma unroll
            for (int k = 0; k < 16; ++k) {
                const float4 w = wr[k], q4 = qv[k];
                acc += w.x*q4.x + w.y*q4.y + w.z*q4.z + w.w*q4.w;
            }
            kq[j] = acc;
            if (j >= HALF) ws[WS_KQ + bh*EMB + j] = acc;
        }
    }
    __syncthreads();
    // phase 3: coef
    {
        float a[IN_DIM] = {0.f,0.f,0.f,0.f,0.f,0.f,0.f,0.f};
        float c0 = 0.f, c1 = 0.f;
        #pragma unroll
        for (int r = 0; r < 2; ++r) {
            const int e = tid + r*256;
            const float kv = kq[e];
            #pragma unroll
            for (int i = 0; i < IN_DIM; ++i) a[i] += Wf[i*EMB + e]*kv;
            c0 += bf[e]*kv;
            if (r == 0) { c0 += bl[e]*kv; c1 += Wl[e]*kv; }
        }
        if (tid < HDIM) c0 += qc[tid]*bk[h*HDIM + tid];
        #pragma unroll
        for (int off = 32; off >= 1; off >>= 1) {
            #pragma unroll
            for (int i = 0; i < IN_DIM; ++i) a[i] += __shfl_xor(a[i], off, 64);
            c0 += __shfl_xor(c0, off, 64);
            c1 += __shfl_xor(c1, off, 64);
        }
        const int wid = tid >> 6, lane = tid & 63;
        if (lane == 0) {
            #pragma unroll
            for (int i = 0; i < IN_DIM; ++i) red10[wid][i] = a[i];
            red10[wid][8] = c0; red10[wid][9] = c1;
        }
        __syncthreads();
        if (tid < 10)
            ws[WS_COEF1 + bh*12 + tid] =
                red10[0][tid]+red10[1][tid]+red10[2][tid]+red10[3][tid];
    }
}

// K2: per (b, 64-t chunk): sin table once -> scores(8h) -> local softmax stats
//     -> unnormalized S-partials.
__global__ __launch_bounds__(256) void k_part(
    const float* __restrict__ feat, const float* __restrict__ ts,
    const float* __restrict__ Wp, const float* __restrict__ bp,
    const float* __restrict__ tdp, float* __restrict__ ws)
{
    const int c = blockIdx.x;      // 0..31
    const int b = blockIdx.y;
    const int tid = threadIdx.x;   // 256
    const int t0 = c*64;

    __shared__ float sin_l[256*65];            // [j][t] stride 65 (bank-safe)
    __shared__ __align__(16) float kqh[HEADS][256];
    __shared__ __align__(16) float w_l[64*8];  // [t][h]
    __shared__ float tv_l[64];
    __shared__ float f_l[64*9];                // [t][i] stride 9
    __shared__ float cf[96];                   // [h][12]

    if (tid < 64) tv_l[tid] = ts[b*S + t0 + tid];
    for (int idx = tid; idx < 64*IN_DIM; idx += 256) {
        const int tt = idx >> 3, i = idx & 7;
        f_l[tt*9 + i] = feat[(b*S + t0 + tt)*IN_DIM + i];
    }
    for (int idx = tid; idx < HEADS*256; idx += 256)
        ((float*)kqh)[idx] = ws[WS_KQ + (b*HEADS + (idx >> 8))*EMB + HALF + (idx & 255)];
    if (tid < 96) cf[tid] = ws[WS_COEF1 + b*96 + tid];
    const float tl = ts[b*S + (S-1)];
    const float td = tdp[0];
    __syncthreads();

    // phase 1: sin table
    {
        const float wj = Wp[tid], bj = bp[tid];
        float* srow = sin_l + tid*65;
        #pragma unroll 4
        for (int tt = 0; tt < 64; ++tt)
            srow[tt] = __sinf(tv_l[tt]*wj + bj);
    }
    __syncthreads();

    // phase 2: scores for (t, h0) and (t, h0+4)
    const int t = tid & 63, h0 = tid >> 6;
    const float tv = tv_l[t];
    float fv[IN_DIM];
    #pragma unroll
    for (int i = 0; i < IN_DIM; ++i) fv[i] = f_l[t*9 + i];
    const float dec = __expf(-td*fabsf(tl - tv));
    float sc[2];
    {
        float acc0 = 0.f, acc1 = 0.f;
        const float4* kq0 = (const float4*)&kqh[h0][0];
        const float4* kq1 = (const float4*)&kqh[h0+4][0];
        #pragma unroll 4
        for (int j4 = 0; j4 < 64; ++j4) {
            const float s0 = sin_l[(j4*4+0)*65 + t];
            const float s1 = sin_l[(j4*4+1)*65 + t];
            const float s2 = sin_l[(j4*4+2)*65 + t];
            const float s3 = sin_l[(j4*4+3)*65 + t];
            const float4 ka = kq0[j4], kb = kq1[j4];
            acc0 += s0*ka.x + s1*ka.y + s2*ka.z + s3*ka.w;
            acc1 += s0*kb.x + s1*kb.y + s2*kb.z + s3*kb.w;
        }
        #pragma unroll
        for (int p = 0; p < 2; ++p) {
            const int h = h0 + p*4;
            float base = cf[h*12+8] + tv*cf[h*12+9];
            #pragma unroll
            for (int i = 0; i < IN_DIM; ++i) base += fv[i]*cf[h*12+i];
            sc[p] = (base + ((p == 0) ? acc0 : acc1))*0.125f*dec;
        }
    }
    // phase 3: per-wave local softmax stats
    #pragma unroll
    for (int p = 0; p < 2; ++p) {
        const int h = h0 + p*4;
        float m = sc[p];
        #pragma unroll
        for (int off = 32; off >= 1; off >>= 1) m = fmaxf(m, __shfl_xor(m, off, 64));
        const float w = __expf(sc[p] - m);
        float Z = w, ta = w*tv;
        float fa[IN_DIM];
        #pragma unroll
        for (int i = 0; i < IN_DIM; ++i) fa[i] = w*fv[i];
        #pragma unroll
        for (int off = 32; off >= 1; off >>= 1) {
            Z  += __shfl_xor(Z,  off, 64);
            ta += __shfl_xor(ta, off, 64);
            #pragma unroll
            for (int i = 0; i < IN_DIM; ++i) fa[i] += __shfl_xor(fa[i], off, 64);
        }
        w_l[t*8 + h] = w;
        if (t == 0) {
            float* pm = ws + WS_PM + ((b*NCHUNK + c)*HEADS + h)*16;
            pm[0] = m; pm[1] = Z; pm[2] = ta;
            #pragma unroll
            for (int i = 0; i < IN_DIM; ++i) pm[3+i] = fa[i];
        }
    }
    __syncthreads();
    // phase 4: S_c[h][j] = sum_t w[t][h] * sin[j][t]
    {
        const int j = tid;
        float accS[HEADS] = {0.f,0.f,0.f,0.f,0.f,0.f,0.f,0.f};
        const float4* wv4 = (const float4*)w_l;
        const float* scol = sin_l + j*65;
        #pragma unroll 4
        for (int tt = 0; tt < 64; ++tt) {
            const float sv = scol[tt];
            const float4 wa = wv4[tt*2], wb = wv4[tt*2+1];
            accS[0] += wa.x*sv; accS[1] += wa.y*sv; accS[2] += wa.z*sv; accS[3] += wa.w*sv;
            accS[4] += wb.x*sv; accS[5] += wb.y*sv; accS[6] += wb.z*sv; accS[7] += wb.w*sv;
        }
        const int base = WS_PS + ((b*NCHUNK + c)*HEADS)*256 + j;
        #pragma unroll
        for (int h = 0; h < HEADS; ++h) ws[base + h*256] = accS[h];
    }
}

// K3: per b (8 blocks x 1024 thr): flash merge (8 head-groups of 128 thr)
//     -> wx[8][512] in LDS -> Wv gemv -> Wo gemv -> W1+relu -> W2 -> logits
__global__ __launch_bounds__(1024) void k_cde(
    const float* __restrict__ Wf, const float* __restrict__ bf,
    const float* __restrict__ Wl, const float* __restrict__ bl,
    const float* __restrict__ Wv, const float* __restrict__ bv,
    const float* __restrict__ Wo, const float* __restrict__ bo,
    const float* __restrict__ W1, const float* __restrict__ b1,
    const float* __restrict__ W2, const float* __restrict__ b2,
    const float* __restrict__ ws, float* __restrict__ out)
{
    const int b = blockIdx.x;
    const int tid = threadIdx.x;
    const int g  = tid >> 7;       // head group 0..7
    const int tg = tid & 127;

    __shared__ float pmL[HEADS][NCHUNK][12];
    __shared__ float alL[HEADS][NCHUNK];
    __shared__ float cfL[HEADS][10];
    __shared__ float wxL[HEADS][EMB];
    __shared__ float redL[2][EMB];
    __shared__ float ohL[EMB];
    __shared__ float opL[EMB];
    __shared__ float hhL[HALF];
    __shared__ float red3[4][3];

    // ---- phase C: per-head flash merge (group g handles head g) ----
    for (int idx = tg; idx < NCHUNK*11; idx += 128) {
        const int c = idx / 11, k = idx % 11;
        pmL[g][c][k] = ws[WS_PM + ((b*NCHUNK + c)*HEADS + g)*16 + k];
    }
    __syncthreads();
    float m = pmL[g][0][0];
    #pragma unroll 8
    for (int c = 1; c < NCHUNK; ++c) m = fmaxf(m, pmL[g][c][0]);
    if (tg < NCHUNK) alL[g][tg] = __expf(pmL[g][tg][0] - m);
    __syncthreads();
    float Z = 0.f;
    #pragma unroll 8
    for (int c = 0; c < NCHUNK; ++c) Z += alL[g][c]*pmL[g][c][1];
    const float inv = 1.f/Z;
    if (tg < 9) {
        const int k = (tg == 8) ? 2 : 3 + tg;   // ta at [2], fa_i at [3+i]
        float acc = 0.f;
        #pragma unroll 8
        for (int c = 0; c < NCHUNK; ++c) acc += alL[g][c]*pmL[g][c][k];
        cfL[g][(tg == 8) ? 8 : tg] = acc*inv;
    }
    __syncthreads();
    // wx assembly: 4 elems per thread (e = tg, tg+128, tg+256, tg+384)
    #pragma unroll
    for (int r = 0; r < 4; ++r) {
        const int e = tg + r*128;
        float val = bf[e];
        #pragma unroll
        for (int i = 0; i < IN_DIM; ++i) val += cfL[g][i]*Wf[i*EMB + e];
        if (e < HALF) {
            val += cfL[g][8]*Wl[e] + bl[e];
        } else {
            const int j = e - HALF;
            float acc = 0.f;
            #pragma unroll 8
            for (int c = 0; c < NCHUNK; ++c)
                acc += alL[g][c]*ws[WS_PS + ((b*NCHUNK + c)*HEADS + g)*256 + j];
            val += acc*inv;
        }
        wxL[g][e] = val;
    }
    __syncthreads();

    // ---- Wv gemv: oh[e] = wx[e>>6][:] . Wv[:,e] + bv[e], 2-way split-K ----
    {
        const int e = tid & 511, half = tid >> 9;
        const int h = e >> 6;
        float acc = 0.f;
        #pragma unroll 8
        for (int j = half*256; j < half*256 + 256; ++j)
            acc += wxL[h][j]*Wv[j*EMB + e];
        redL[half][e] = acc;
    }
    __syncthreads();
    if (tid < EMB) ohL[tid] = redL[0][tid] + redL[1][tid] + bv[tid];
    __syncthreads();

    // ---- Wo gemv: op = oh @ Wo + bo, 2-way split-K ----
    {
        const int e = tid & 511, half = tid >> 9;
        float acc = 0.f;
        #pragma unroll 8
        for (int j = half*256; j < half*256 + 256; ++j)
            acc += ohL[j]*Wo[j*EMB + e];
        redL[half][e] = acc;
    }
    __syncthreads();
    if (tid < EMB) opL[tid] = redL[0][tid] + redL[1][tid] + bo[tid];
    __syncthreads();

    // ---- W1 + relu: hh[m] = relu(op @ W1 + b1), 4-way split-K ----
    {
        const int mm = tid & 255, jq = tid >> 8;
        float acc = 0.f;
        #pragma unroll 8
        for (int j = jq*128; j < jq*128 + 128; ++j)
            acc += opL[j]*W1[j*HALF + mm];
        ((float*)redL)[jq*HALF + mm] = acc;   // reuse redL as [4][256]
    }
    __syncthreads();
    if (tid < HALF) {
        const float* r4 = (const float*)redL;
        hhL[tid] = fmaxf(r4[tid] + r4[HALF+tid] + r4[2*HALF+tid] + r4[3*HALF+tid]
                         + b1[tid], 0.f);
    }
    __syncthreads();

    // ---- W2: logits ----
    if (tid < HALF) {
        const float hv = hhL[tid];
        float p0 = hv*W2[tid*NCLS + 0];
        float p1 = hv*W2[tid*NCLS + 1];
        float p2 = hv*W2[tid*NCLS + 2];
        #pragma unroll
        for (int off = 32; off >= 1; off >>= 1) {
            p0 += __shfl_xor(p0, off, 64);
            p1 += __shfl_xor(p1, off, 64);
            p2 += __shfl_xor(p2, off, 64);
        }
        const int wid = tid >> 6;
        if ((tid & 63) == 0) { red3[wid][0] = p0; red3[wid][1] = p1; red3[wid][2] = p2; }
    }
    __syncthreads();
    if (tid < NCLS)
        out[b*NCLS + tid] = red3[0][tid]+red3[1][tid]+red3[2][tid]+red3[3][tid] + b2[tid];
}

extern "C" void kernel_launch(void* const* d_in, const int* in_sizes, int n_in,
                              void* d_out, int out_size, void* d_ws, size_t ws_size,
                              hipStream_t stream)
{
    const float* feat = (const float*)d_in[0];
    const float* ts   = (const float*)d_in[1];
    const float* Wf = (const float*)d_in[2];
    const float* bf = (const float*)d_in[3];
    const float* Wl = (const float*)d_in[4];
    const float* bl = (const float*)d_in[5];
    const float* Wp = (const float*)d_in[6];
    const float* bp = (const float*)d_in[7];
    const float* Wq = (const float*)d_in[8];
    const float* bq = (const float*)d_in[9];
    const float* Wk = (const float*)d_in[10];
    const float* bk = (const float*)d_in[11];
    const float* Wv = (const float*)d_in[12];
    const float* bv = (const float*)d_in[13];
    const float* Wo = (const float*)d_in[14];
    const float* bo = (const float*)d_in[15];
    const float* td = (const float*)d_in[16];
    const float* W1 = (const float*)d_in[17];
    const float* b1 = (const float*)d_in[18];
    const float* W2 = (const float*)d_in[19];
    const float* b2 = (const float*)d_in[20];
    float* ws = (float*)d_ws;
    float* out = (float*)d_out;

    hipLaunchKernelGGL(k_head, dim3(HEADS, B), dim3(256),  0, stream,
                       feat, ts, Wf, bf, Wl, bl, Wp, bp, Wq, bq, Wk, bk, ws);
    hipLaunchKernelGGL(k_part, dim3(NCHUNK, B),dim3(256),  0, stream,
                       feat, ts, Wp, bp, td, ws);
    hipLaunchKernelGGL(k_cde,  dim3(B),        dim3(1024), 0, stream,
                       Wf, bf, Wl, bl, Wv, bv, Wo, bo, W1, b1, W2, b2, ws, out);
}

// Round 7
// 48.594 us; speedup vs baseline: 5.4142x; 1.2649x over previous
//
#include <hip/hip_runtime.h>
#include <hip/hip_bf16.h>
#include <math.h>

#define B 8
#define S 2048
#define IN_DIM 8
#define EMB 512
#define HEADS 8
#define HDIM 64
#define HALF 256
#define NCLS 3
#define NCHUNK 64   // t-chunks of 32
#define CT 32       // timesteps per chunk

// workspace layout (float offsets)
#define WS_KQ    0            // [B][HEADS][EMB] (hi half used)        = 32768
#define WS_COEF1 32768        // [B][HEADS][12]  (a[0..7], c0, c1)     = 768
#define WS_PM    33536        // [B][64][HEADS][16] (m,Z,ta,fa[8])     = 65536
#define WS_PS    99072        // [B][64][HEADS][256] S-partials        = 1048576
#define WS_POP   1147648      // [B][HEADS][EMB] Wo partials           = 32768

// K1: per (b,h): recompute x_last -> q-chunk(h) -> kq[b][h][:] -> coef
__global__ __launch_bounds__(256) void k_head(
    const float* __restrict__ feat, const float* __restrict__ ts,
    const float* __restrict__ Wf, const float* __restrict__ bf,
    const float* __restrict__ Wl, const float* __restrict__ bl,
    const float* __restrict__ Wp, const float* __restrict__ bp,
    const float* __restrict__ Wq, const float* __restrict__ bq,
    const float* __restrict__ Wk, const float* __restrict__ bk,
    float* __restrict__ ws)
{
    const int h = blockIdx.x;
    const int b = blockIdx.y;
    const int bh = b*HEADS + h;
    const int tid = threadIdx.x;
    __shared__ float xl[EMB];
    __shared__ __align__(16) float qc[HDIM];
    __shared__ float kq[EMB];
    __shared__ float red[4][64];
    __shared__ float red10[4][12];

    // phase 0: x at last position
    {
        const float tl = ts[b*S + (S-1)];
        float fv[IN_DIM];
        #pragma unroll
        for (int i = 0; i < IN_DIM; ++i) fv[i] = feat[(b*S + (S-1))*IN_DIM + i];
        #pragma unroll
        for (int r = 0; r < 2; ++r) {
            const int e = tid + r*256;
            float acc = bf[e];
            #pragma unroll
            for (int i = 0; i < IN_DIM; ++i) acc += fv[i]*Wf[i*EMB + e];
            if (r == 0) acc += tl*Wl[e] + bl[e];
            else        acc += __sinf(tl*Wp[e-HALF] + bp[e-HALF]);
            xl[e] = acc;
        }
    }
    __syncthreads();
    // phase 1: q-chunk for this head (4-way split-K)
    {
        const int eo = tid & 63, jq = tid >> 6;
        float acc = (jq == 0) ? bq[h*HDIM + eo] : 0.f;
        #pragma unroll 8
        for (int j = jq*128; j < jq*128 + 128; ++j)
            acc += xl[j]*Wq[j*EMB + h*HDIM + eo];
        red[jq][eo] = acc;
    }
    __syncthreads();
    if (tid < HDIM) qc[tid] = red[0][tid]+red[1][tid]+red[2][tid]+red[3][tid];
    __syncthreads();
    // phase 2: kq[j] = Wk[j, h*64:+64] . qc
    {
        #pragma unroll
        for (int r = 0; r < 2; ++r) {
            const int j = tid + r*256;
            const float4* wr = (const float4*)(Wk + j*EMB + h*HDIM);
            const float4* qv = (const float4*)qc;
            float acc = 0.f;
            #pragma unroll
            for (int k = 0; k < 16; ++k) {
                const float4 w = wr[k], q4 = qv[k];
                acc += w.x*q4.x + w.y*q4.y + w.z*q4.z + w.w*q4.w;
            }
            kq[j] = acc;
            if (j >= HALF) ws[WS_KQ + bh*EMB + j] = acc;
        }
    }
    __syncthreads();
    // phase 3: coef
    {
        float a[IN_DIM] = {0.f,0.f,0.f,0.f,0.f,0.f,0.f,0.f};
        float c0 = 0.f, c1 = 0.f;
        #pragma unroll
        for (int r = 0; r < 2; ++r) {
            const int e = tid + r*256;
            const float kv = kq[e];
            #pragma unroll
            for (int i = 0; i < IN_DIM; ++i) a[i] += Wf[i*EMB + e]*kv;
            c0 += bf[e]*kv;
            if (r == 0) { c0 += bl[e]*kv; c1 += Wl[e]*kv; }
        }
        if (tid < HDIM) c0 += qc[tid]*bk[h*HDIM + tid];
        #pragma unroll
        for (int off = 32; off >= 1; off >>= 1) {
            #pragma unroll
            for (int i = 0; i < IN_DIM; ++i) a[i] += __shfl_xor(a[i], off, 64);
            c0 += __shfl_xor(c0, off, 64);
            c1 += __shfl_xor(c1, off, 64);
        }
        const int wid = tid >> 6, lane = tid & 63;
        if (lane == 0) {
            #pragma unroll
            for (int i = 0; i < IN_DIM; ++i) red10[wid][i] = a[i];
            red10[wid][8] = c0; red10[wid][9] = c1;
        }
        __syncthreads();
        if (tid < 10)
            ws[WS_COEF1 + bh*12 + tid] =
                red10[0][tid]+red10[1][tid]+red10[2][tid]+red10[3][tid];
    }
}

// K2: per (b, 32-t chunk): sin table once -> scores(8h) -> local softmax stats
//     -> unnormalized S-partials. 512 blocks for MLP.
__global__ __launch_bounds__(256) void k_part(
    const float* __restrict__ feat, const float* __restrict__ ts,
    const float* __restrict__ Wp, const float* __restrict__ bp,
    const float* __restrict__ tdp, float* __restrict__ ws)
{
    const int c = blockIdx.x;      // 0..63
    const int b = blockIdx.y;
    const int tid = threadIdx.x;   // 256
    const int t0 = c*CT;

    __shared__ float sin_l[256*33];            // [j][t] stride 33 (bank-safe)
    __shared__ __align__(16) float kqh[HEADS][256];
    __shared__ __align__(16) float w_l[CT*8];  // [t][h]
    __shared__ float tv_l[CT];
    __shared__ float f_l[CT*9];                // [t][i] stride 9
    __shared__ float cf[96];                   // [h][12]

    if (tid < CT) tv_l[tid] = ts[b*S + t0 + tid];
    for (int idx = tid; idx < CT*IN_DIM; idx += 256) {
        const int tt = idx >> 3, i = idx & 7;
        f_l[tt*9 + i] = feat[(b*S + t0 + tt)*IN_DIM + i];
    }
    for (int idx = tid; idx < HEADS*256; idx += 256)
        ((float*)kqh)[idx] = ws[WS_KQ + (b*HEADS + (idx >> 8))*EMB + HALF + (idx & 255)];
    if (tid < 96) cf[tid] = ws[WS_COEF1 + b*96 + tid];
    const float tl = ts[b*S + (S-1)];
    const float td = tdp[0];
    __syncthreads();

    // phase 1: sin table (each value computed once, used for scores AND S)
    {
        const float wj = Wp[tid], bj = bp[tid];
        float* srow = sin_l + tid*33;
        #pragma unroll 4
        for (int tt = 0; tt < CT; ++tt)
            srow[tt] = __sinf(tv_l[tt]*wj + bj);
    }
    __syncthreads();

    // phase 2: score for (t, h), one head per thread (32 t x 8 h = 256)
    const int t = tid & (CT-1), h = tid >> 5;
    const float tv = tv_l[t];
    float fv[IN_DIM];
    #pragma unroll
    for (int i = 0; i < IN_DIM; ++i) fv[i] = f_l[t*9 + i];
    const float dec = __expf(-td*fabsf(tl - tv));
    float sc;
    {
        float acc = 0.f;
        const float4* kq4 = (const float4*)&kqh[h][0];
        #pragma unroll 4
        for (int j4 = 0; j4 < 64; ++j4) {
            const float s0 = sin_l[(j4*4+0)*33 + t];
            const float s1 = sin_l[(j4*4+1)*33 + t];
            const float s2 = sin_l[(j4*4+2)*33 + t];
            const float s3 = sin_l[(j4*4+3)*33 + t];
            const float4 ka = kq4[j4];
            acc += s0*ka.x + s1*ka.y + s2*ka.z + s3*ka.w;
        }
        float base = cf[h*12+8] + tv*cf[h*12+9];
        #pragma unroll
        for (int i = 0; i < IN_DIM; ++i) base += fv[i]*cf[h*12+i];
        sc = (base + acc)*0.125f*dec;
    }
    // phase 3: per-half-wave (= per head) local softmax stats over 32 t
    {
        float m = sc;
        #pragma unroll
        for (int off = 16; off >= 1; off >>= 1) m = fmaxf(m, __shfl_xor(m, off, 64));
        const float w = __expf(sc - m);
        float Z = w, ta = w*tv;
        float fa[IN_DIM];
        #pragma unroll
        for (int i = 0; i < IN_DIM; ++i) fa[i] = w*fv[i];
        #pragma unroll
        for (int off = 16; off >= 1; off >>= 1) {
            Z  += __shfl_xor(Z,  off, 64);
            ta += __shfl_xor(ta, off, 64);
            #pragma unroll
            for (int i = 0; i < IN_DIM; ++i) fa[i] += __shfl_xor(fa[i], off, 64);
        }
        w_l[t*8 + h] = w;
        if (t == 0) {
            float* pm = ws + WS_PM + ((b*NCHUNK + c)*HEADS + h)*16;
            pm[0] = m; pm[1] = Z; pm[2] = ta;
            #pragma unroll
            for (int i = 0; i < IN_DIM; ++i) pm[3+i] = fa[i];
        }
    }
    __syncthreads();
    // phase 4: S_c[h][j] = sum_t w[t][h] * sin[j][t]  (unnormalized)
    {
        const int j = tid;
        float accS[HEADS] = {0.f,0.f,0.f,0.f,0.f,0.f,0.f,0.f};
        const float4* wv4 = (const float4*)w_l;
        const float* scol = sin_l + j*33;
        #pragma unroll 4
        for (int tt = 0; tt < CT; ++tt) {
            const float sv = scol[tt];
            const float4 wa = wv4[tt*2], wb = wv4[tt*2+1];
            accS[0] += wa.x*sv; accS[1] += wa.y*sv; accS[2] += wa.z*sv; accS[3] += wa.w*sv;
            accS[4] += wb.x*sv; accS[5] += wb.y*sv; accS[6] += wb.z*sv; accS[7] += wb.w*sv;
        }
        const int base = WS_PS + ((b*NCHUNK + c)*HEADS)*256 + j;
        #pragma unroll
        for (int hh = 0; hh < HEADS; ++hh) ws[base + hh*256] = accS[hh];
    }
}

// K3: per (b,h): flash merge -> wx -> Wv gemv (oh chunk) -> Wo PARTIAL:
//     pop[b][h][e] = sum_d oh_c[d] * Wo[h*64+d, e]
__global__ __launch_bounds__(256) void k_ohw(
    const float* __restrict__ Wf, const float* __restrict__ bf,
    const float* __restrict__ Wl, const float* __restrict__ bl,
    const float* __restrict__ Wv, const float* __restrict__ bv,
    const float* __restrict__ Wo, float* __restrict__ ws)
{
    const int h = blockIdx.x;
    const int b = blockIdx.y;
    const int tid = threadIdx.x;
    __shared__ float pmL[NCHUNK][12];
    __shared__ float al[NCHUNK];
    __shared__ float cfL[10];
    __shared__ float wx[EMB];
    __shared__ float red[4][64];
    __shared__ __align__(16) float oh_c[HDIM];

    for (int idx = tid; idx < NCHUNK*11; idx += 256) {
        const int c = idx / 11, k = idx % 11;
        pmL[c][k] = ws[WS_PM + ((b*NCHUNK + c)*HEADS + h)*16 + k];
    }
    __syncthreads();
    float m = pmL[0][0];
    #pragma unroll 8
    for (int c = 1; c < NCHUNK; ++c) m = fmaxf(m, pmL[c][0]);
    if (tid < NCHUNK) al[tid] = __expf(pmL[tid][0] - m);
    __syncthreads();
    float Z = 0.f;
    #pragma unroll 8
    for (int c = 0; c < NCHUNK; ++c) Z += al[c]*pmL[c][1];
    const float inv = 1.f/Z;
    if (tid < 9) {
        const int k = (tid == 8) ? 2 : 3 + tid;   // ta at [2], fa_i at [3+i]
        float acc = 0.f;
        #pragma unroll 8
        for (int c = 0; c < NCHUNK; ++c) acc += al[c]*pmL[c][k];
        cfL[(tid == 8) ? 8 : tid] = acc*inv;
    }
    __syncthreads();
    // wx assembly
    {
        const int j = tid;
        float acc = 0.f;
        #pragma unroll 8
        for (int c = 0; c < NCHUNK; ++c)
            acc += al[c]*ws[WS_PS + ((b*NCHUNK + c)*HEADS + h)*256 + j];
        float vh = bf[HALF + j] + acc*inv;
        float vl = bf[j] + cfL[8]*Wl[j] + bl[j];
        #pragma unroll
        for (int i = 0; i < IN_DIM; ++i) {
            vh += cfL[i]*Wf[i*EMB + HALF + j];
            vl += cfL[i]*Wf[i*EMB + j];
        }
        wx[j] = vl;
        wx[HALF + j] = vh;
    }
    __syncthreads();
    // Wv gemv for this head's 64 cols (4-way split-K)
    {
        const int eo = tid & 63, jq = tid >> 6;
        const int e = h*HDIM + eo;
        float acc = 0.f;
        #pragma unroll 8
        for (int j = jq*128; j < jq*128 + 128; ++j)
            acc += wx[j]*Wv[j*EMB + e];
        red[jq][eo] = acc;
    }
    __syncthreads();
    if (tid < 64)
        oh_c[tid] = red[0][tid]+red[1][tid]+red[2][tid]+red[3][tid] + bv[h*HDIM + tid];
    __syncthreads();
    // Wo partial: pop[e] = sum_{d<64} oh_c[d] * Wo[(h*64+d)*EMB + e]
    {
        #pragma unroll
        for (int r = 0; r < 2; ++r) {
            const int e = tid + r*256;
            float acc = 0.f;
            #pragma unroll 8
            for (int d = 0; d < HDIM; ++d)
                acc += oh_c[d]*Wo[(h*HDIM + d)*EMB + e];
            ws[WS_POP + (b*HEADS + h)*EMB + e] = acc;
        }
    }
}

// K4: per b: op = sum_h pop + bo -> hh = relu(op @ W1 + b1) -> logits
__global__ __launch_bounds__(1024) void k_tail2(
    const float* __restrict__ bo,
    const float* __restrict__ W1, const float* __restrict__ b1,
    const float* __restrict__ W2, const float* __restrict__ b2,
    const float* __restrict__ ws, float* __restrict__ out)
{
    const int b = blockIdx.x;
    const int tid = threadIdx.x;
    __shared__ float opL[EMB];
    __shared__ float red[4][HALF];
    __shared__ float hhL[HALF];
    __shared__ float red3[4][3];

    if (tid < EMB) {
        float acc = bo[tid];
        #pragma unroll
        for (int h = 0; h < HEADS; ++h)
            acc += ws[WS_POP + (b*HEADS + h)*EMB + tid];
        opL[tid] = acc;
    }
    __syncthreads();
    {
        const int mm = tid & 255, jq = tid >> 8;
        float acc = 0.f;
        #pragma unroll 8
        for (int j = jq*128; j < jq*128 + 128; ++j)
            acc += opL[j]*W1[j*HALF + mm];
        red[jq][mm] = acc;
    }
    __syncthreads();
    if (tid < HALF)
        hhL[tid] = fmaxf(red[0][tid]+red[1][tid]+red[2][tid]+red[3][tid] + b1[tid], 0.f);
    __syncthreads();
    if (tid < HALF) {
        const float hv = hhL[tid];
        float p0 = hv*W2[tid*NCLS + 0];
        float p1 = hv*W2[tid*NCLS + 1];
        float p2 = hv*W2[tid*NCLS + 2];
        #pragma unroll
        for (int off = 32; off >= 1; off >>= 1) {
            p0 += __shfl_xor(p0, off, 64);
            p1 += __shfl_xor(p1, off, 64);
            p2 += __shfl_xor(p2, off, 64);
        }
        const int wid = tid >> 6;
        if ((tid & 63) == 0) { red3[wid][0] = p0; red3[wid][1] = p1; red3[wid][2] = p2; }
    }
    __syncthreads();
    if (tid < NCLS)
        out[b*NCLS + tid] = red3[0][tid]+red3[1][tid]+red3[2][tid]+red3[3][tid] + b2[tid];
}

extern "C" void kernel_launch(void* const* d_in, const int* in_sizes, int n_in,
                              void* d_out, int out_size, void* d_ws, size_t ws_size,
                              hipStream_t stream)
{
    const float* feat = (const float*)d_in[0];
    const float* ts   = (const float*)d_in[1];
    const float* Wf = (const float*)d_in[2];
    const float* bf = (const float*)d_in[3];
    const float* Wl = (const float*)d_in[4];
    const float* bl = (const float*)d_in[5];
    const float* Wp = (const float*)d_in[6];
    const float* bp = (const float*)d_in[7];
    const float* Wq = (const float*)d_in[8];
    const float* bq = (const float*)d_in[9];
    const float* Wk = (const float*)d_in[10];
    const float* bk = (const float*)d_in[11];
    const float* Wv = (const float*)d_in[12];
    const float* bv = (const float*)d_in[13];
    const float* Wo = (const float*)d_in[14];
    const float* bo = (const float*)d_in[15];
    const float* td = (const float*)d_in[16];
    const float* W1 = (const float*)d_in[17];
    const float* b1 = (const float*)d_in[18];
    const float* W2 = (const float*)d_in[19];
    const float* b2 = (const float*)d_in[20];
    float* ws = (float*)d_ws;
    float* out = (float*)d_out;

    hipLaunchKernelGGL(k_head,  dim3(HEADS, B),  dim3(256),  0, stream,
                       feat, ts, Wf, bf, Wl, bl, Wp, bp, Wq, bq, Wk, bk, ws);
    hipLaunchKernelGGL(k_part,  dim3(NCHUNK, B), dim3(256),  0, stream,
                       feat, ts, Wp, bp, td, ws);
    hipLaunchKernelGGL(k_ohw,   dim3(HEADS, B),  dim3(256),  0, stream,
                       Wf, bf, Wl, bl, Wv, bv, Wo, ws);
    hipLaunchKernelGGL(k_tail2, dim3(B),         dim3(1024), 0, stream,
                       bo, W1, b1, W2, b2, ws, out);
}